// Round 4
// baseline (1127.248 us; speedup 1.0000x reference)
//
#include <hip/hip_runtime.h>

#define NNODES 100000
#define NEDGES 1600000
#define FDIM 128
#define NGRAPHS 128
#define NLAYERS 4
#define NCLASS 10
#define NB_SCAN ((NNODES + 255) / 256)
#define POOL_NPB 128
#define LDAG 264    // A-in-LDS row stride (elems): 528 B = 132 dw ≡ 4 mod 32 -> 2-way alias (free)
#define LDB 40      // B staging row stride (elems)

typedef __attribute__((ext_vector_type(8))) short bf16x8;
typedef __attribute__((ext_vector_type(4))) float f32x4;
typedef unsigned short u16;
typedef unsigned int u32;

__device__ __forceinline__ u16 f2bf(float f) {
    u32 u = __float_as_uint(f);
    u += 0x7fffu + ((u >> 16) & 1u);   // round-to-nearest-even
    return (u16)(u >> 16);
}
__device__ __forceinline__ float bf_lo(u32 u) { return __uint_as_float(u << 16); }
__device__ __forceinline__ float bf_hi(u32 u) { return __uint_as_float(u & 0xffff0000u); }
__device__ __forceinline__ u32 pack_bf(float a, float b) {
    return (u32)f2bf(a) | ((u32)f2bf(b) << 16);
}

// ---------------- dtype conversion ----------------

__global__ __launch_bounds__(256) void conv_x(const float* __restrict__ x,
                                              u16* __restrict__ xb) {
    int i = (blockIdx.x * 256 + threadIdx.x) * 4;
    if (i < NNODES * FDIM) {
        float4 v = *(const float4*)(x + i);
        u32 p0 = pack_bf(v.x, v.y), p1 = pack_bf(v.z, v.w);
        *(u32*)(xb + i) = p0;
        *(u32*)(xb + i + 2) = p1;
    }
}

// Wcat[l][n][k]: k<128 -> Wrel[k][n], k>=128 -> Wroot[k-128][n]  (transposed, concat)
__global__ __launch_bounds__(256) void conv_w(const float* __restrict__ W1_rel,
                                              const float* __restrict__ W1_root,
                                              const float* __restrict__ Wc_rel,
                                              const float* __restrict__ Wc_root,
                                              u16* __restrict__ Wcat) {
    int idx = blockIdx.x * 256 + threadIdx.x;
    if (idx >= NLAYERS * 256 * FDIM) return;
    int n = idx & 127;
    int k = (idx >> 7) & 255;
    int l = idx >> 15;
    const float* Wr = (l == 0) ? W1_rel  : Wc_rel  + (size_t)(l - 1) * FDIM * FDIM;
    const float* Wt = (l == 0) ? W1_root : Wc_root + (size_t)(l - 1) * FDIM * FDIM;
    float v = (k < 128) ? Wr[(size_t)k * FDIM + n] : Wt[(size_t)(k - 128) * FDIM + n];
    Wcat[(size_t)l * 32768 + (size_t)n * 256 + k] = f2bf(v);
}

// ---------------- graph structure ----------------

__global__ __launch_bounds__(192) void graph_ptr_kernel(const int* __restrict__ batch,
                                                        int* __restrict__ gptr) {
    int g = threadIdx.x;
    if (g > NGRAPHS) return;
    int lo = 0, hi = NNODES;
    while (lo < hi) {
        int mid = (lo + hi) >> 1;
        if (batch[mid] < g) lo = mid + 1; else hi = mid;
    }
    gptr[g] = lo;
}

__global__ __launch_bounds__(256) void deg_kernel(const int* __restrict__ dst,
                                                  int* __restrict__ deg) {
    int e = blockIdx.x * 256 + threadIdx.x;
    if (e < NEDGES) atomicAdd(&deg[dst[e]], 1);
}

__global__ __launch_bounds__(256) void scan_partial(const int* __restrict__ deg,
                                                    int* __restrict__ partial) {
    __shared__ int sd[256];
    int i = blockIdx.x * 256 + threadIdx.x;
    sd[threadIdx.x] = (i < NNODES) ? deg[i] : 0;
    __syncthreads();
    for (int s = 128; s > 0; s >>= 1) {
        if (threadIdx.x < s) sd[threadIdx.x] += sd[threadIdx.x + s];
        __syncthreads();
    }
    if (threadIdx.x == 0) partial[blockIdx.x] = sd[0];
}

__global__ void scan_prefix(int* __restrict__ partial) {
    if (threadIdx.x == 0) {
        int run = 0;
        for (int b = 0; b < NB_SCAN; ++b) { int v = partial[b]; partial[b] = run; run += v; }
    }
}

__global__ __launch_bounds__(256) void scan_final(const int* __restrict__ deg,
                                                  const int* __restrict__ partial,
                                                  int* __restrict__ row_ptr) {
    __shared__ int sd[256];
    int i = blockIdx.x * 256 + threadIdx.x;
    int v = (i < NNODES) ? deg[i] : 0;
    sd[threadIdx.x] = v;
    __syncthreads();
    for (int s = 1; s < 256; s <<= 1) {
        int add = (threadIdx.x >= s) ? sd[threadIdx.x - s] : 0;
        __syncthreads();
        sd[threadIdx.x] += add;
        __syncthreads();
    }
    if (i < NNODES) {
        int excl = sd[threadIdx.x] - v + partial[blockIdx.x];
        row_ptr[i] = excl;
        if (i == NNODES - 1) row_ptr[NNODES] = excl + v;
    }
}

__global__ __launch_bounds__(256) void fill_csr(const int* __restrict__ src,
                                                const int* __restrict__ dst,
                                                const int* __restrict__ row_ptr,
                                                int* __restrict__ cursor,
                                                int* __restrict__ csr) {
    int e = blockIdx.x * 256 + threadIdx.x;
    if (e < NEDGES) {
        int d = dst[e];
        int p = atomicAdd(&cursor[d], 1);
        csr[row_ptr[d] + p] = src[e];
    }
}

// ---------------- fused layer: gather-agg -> A in LDS -> MFMA GEMM -> relu -> bf16 -------
// A = [agg | hin] (128 rows x K=256) built in LDS; B = Wl [128 n][256 k]; 4 waves 2x2.

__global__ __launch_bounds__(256) void fused_layer(const u16* __restrict__ hinb,
                                                   const int* __restrict__ row_ptr,
                                                   const int* __restrict__ csr,
                                                   const u16* __restrict__ Wl,
                                                   const float* __restrict__ bias,
                                                   u16* __restrict__ houtb) {
    __shared__ u16 Ag[128 * LDAG];   // full A tile; reused as C repack buffer
    __shared__ u16 Bs[128 * LDB];
    const int t = threadIdx.x;
    const int lane = t & 63;
    const int w = t >> 6;
    const int wr = w >> 1, wc = w & 1;
    const int row0 = blockIdx.x * 128;
    const int lr = lane & 15;
    const int lk = (lane >> 4) * 8;

    // ---- phase 1: gather-aggregate (agg half) + self row (root half) ----
    for (int i = 0; i < 32; ++i) {
        const int r = w * 32 + i;
        const int node = row0 + r;
        float ax = 0.f, ay = 0.f;
        u32 self = 0;
        if (node < NNODES) {
            const u32* hrow = (const u32*)(hinb + (size_t)node * FDIM);
            self = hrow[lane];
            int e0 = row_ptr[node], e1 = row_ptr[node + 1];
            int e = e0;
            for (; e + 8 <= e1; e += 8) {
                int s0 = csr[e], s1 = csr[e + 1], s2 = csr[e + 2], s3 = csr[e + 3];
                int s4 = csr[e + 4], s5 = csr[e + 5], s6 = csr[e + 6], s7 = csr[e + 7];
                u32 v0 = ((const u32*)(hinb + (size_t)s0 * FDIM))[lane];
                u32 v1 = ((const u32*)(hinb + (size_t)s1 * FDIM))[lane];
                u32 v2 = ((const u32*)(hinb + (size_t)s2 * FDIM))[lane];
                u32 v3 = ((const u32*)(hinb + (size_t)s3 * FDIM))[lane];
                u32 v4 = ((const u32*)(hinb + (size_t)s4 * FDIM))[lane];
                u32 v5 = ((const u32*)(hinb + (size_t)s5 * FDIM))[lane];
                u32 v6 = ((const u32*)(hinb + (size_t)s6 * FDIM))[lane];
                u32 v7 = ((const u32*)(hinb + (size_t)s7 * FDIM))[lane];
                ax += bf_lo(v0) + bf_lo(v1) + bf_lo(v2) + bf_lo(v3)
                    + bf_lo(v4) + bf_lo(v5) + bf_lo(v6) + bf_lo(v7);
                ay += bf_hi(v0) + bf_hi(v1) + bf_hi(v2) + bf_hi(v3)
                    + bf_hi(v4) + bf_hi(v5) + bf_hi(v6) + bf_hi(v7);
            }
            for (; e + 2 <= e1; e += 2) {
                int s0 = csr[e], s1 = csr[e + 1];
                u32 v0 = ((const u32*)(hinb + (size_t)s0 * FDIM))[lane];
                u32 v1 = ((const u32*)(hinb + (size_t)s1 * FDIM))[lane];
                ax += bf_lo(v0) + bf_lo(v1);
                ay += bf_hi(v0) + bf_hi(v1);
            }
            if (e < e1) {
                int s0 = csr[e];
                u32 v0 = ((const u32*)(hinb + (size_t)s0 * FDIM))[lane];
                ax += bf_lo(v0); ay += bf_hi(v0);
            }
        }
        *(u32*)&Ag[r * LDAG + lane * 2]       = pack_bf(ax, ay);
        *(u32*)&Ag[r * LDAG + 128 + lane * 2] = self;
    }
    __syncthreads();

    // ---- phase 2: K-loop, A from LDS, stage B per 32-k chunk ----
    f32x4 acc[4][4];
#pragma unroll
    for (int m = 0; m < 4; ++m)
#pragma unroll
        for (int n = 0; n < 4; ++n) acc[m][n] = (f32x4){0.f, 0.f, 0.f, 0.f};

    for (int kb = 0; kb < 8; ++kb) {
#pragma unroll
        for (int it = 0; it < 2; ++it) {
            int u = it * 256 + t;
            int r = u >> 2, c = (u & 3) * 8;
            bf16x8 v = *(const bf16x8*)(Wl + (size_t)r * 256 + kb * 32 + c);
            *(bf16x8*)&Bs[r * LDB + c] = v;
        }
        __syncthreads();
        bf16x8 a[4], b[4];
#pragma unroll
        for (int m = 0; m < 4; ++m)
            a[m] = *(const bf16x8*)&Ag[(wr * 64 + m * 16 + lr) * LDAG + kb * 32 + lk];
#pragma unroll
        for (int n = 0; n < 4; ++n)
            b[n] = *(const bf16x8*)&Bs[(wc * 64 + n * 16 + lr) * LDB + lk];
#pragma unroll
        for (int m = 0; m < 4; ++m)
#pragma unroll
            for (int n = 0; n < 4; ++n)
                acc[m][n] = __builtin_amdgcn_mfma_f32_16x16x32_bf16(a[m], b[n], acc[m][n], 0, 0, 0);
        __syncthreads();
    }

    // ---- epilogue: bias + relu + bf16, repack via Ag for coalesced stores ----
#pragma unroll
    for (int m = 0; m < 4; ++m) {
#pragma unroll
        for (int n = 0; n < 4; ++n) {
            int col = wc * 64 + n * 16 + lr;
            float bb = bias[col];
#pragma unroll
            for (int reg = 0; reg < 4; ++reg) {
                int row = wr * 64 + m * 16 + (lane >> 4) * 4 + reg;
                float v = fmaxf(acc[m][n][reg] + bb, 0.f);
                Ag[row * LDAG + col] = f2bf(v);
            }
        }
    }
    __syncthreads();
    {
        int r = t >> 1, half = t & 1;
        if (row0 + r < NNODES) {
#pragma unroll
            for (int j = 0; j < 8; ++j) {
                bf16x8 v = *(const bf16x8*)&Ag[r * LDAG + half * 64 + j * 8];
                *(bf16x8*)(houtb + (size_t)(row0 + r) * FDIM + half * 64 + j * 8) = v;
            }
        }
    }
}

// ---------------- node-parallel mean pool (bf16 in, fp32 atomics; /count in mlp1) --------

__global__ __launch_bounds__(64) void pool_bf(const u16* __restrict__ h,
                                              const int* __restrict__ batch,
                                              float* __restrict__ z, int layer) {
    const int f2 = threadIdx.x;
    const int n0 = blockIdx.x * POOL_NPB;
    int n1 = n0 + POOL_NPB; if (n1 > NNODES) n1 = NNODES;
    __shared__ int bsh[POOL_NPB];
    for (int n = n0 + f2; n < n1; n += 64) bsh[n - n0] = batch[n];
    __syncthreads();
    float s0 = 0.f, s1 = 0.f;
    int g = bsh[0];
    for (int n = n0; n < n1; ++n) {
        int gn = bsh[n - n0];
        if (gn != g) {
            float* zp = &z[(size_t)g * (NLAYERS * FDIM) + layer * FDIM + 2 * f2];
            atomicAdd(zp, s0); atomicAdd(zp + 1, s1);
            s0 = 0.f; s1 = 0.f; g = gn;
        }
        u32 v = ((const u32*)(h + (size_t)n * FDIM))[f2];
        s0 += bf_lo(v); s1 += bf_hi(v);
    }
    float* zp = &z[(size_t)g * (NLAYERS * FDIM) + layer * FDIM + 2 * f2];
    atomicAdd(zp, s0); atomicAdd(zp + 1, s1);
}

// ---------------- final MLP (mean normalization folded into z load) ----------------

__global__ __launch_bounds__(128) void mlp1(const float* __restrict__ z,
                                            const int* __restrict__ gptr,
                                            const float* __restrict__ Wl1,
                                            const float* __restrict__ bl1,
                                            float* __restrict__ z2) {
    int g = blockIdx.x, j = threadIdx.x;
    __shared__ float zs[NLAYERS * FDIM];
    int cnt = gptr[g + 1] - gptr[g]; if (cnt < 1) cnt = 1;
    float invc = 1.0f / (float)cnt;
    for (int k = j; k < NLAYERS * FDIM; k += 128)
        zs[k] = z[(size_t)g * (NLAYERS * FDIM) + k] * invc;
    __syncthreads();
    float s = bl1[j];
    for (int k = 0; k < NLAYERS * FDIM; ++k) s = fmaf(zs[k], Wl1[(size_t)k * FDIM + j], s);
    z2[(size_t)g * FDIM + j] = fmaxf(s, 0.f);
}

__global__ __launch_bounds__(128) void mlp2(const float* __restrict__ z2,
                                            const float* __restrict__ Wl2,
                                            const float* __restrict__ bl2,
                                            float* __restrict__ out) {
    int g = blockIdx.x, c = threadIdx.x;
    __shared__ float zs[FDIM];
    if (threadIdx.x < FDIM) zs[threadIdx.x] = z2[(size_t)g * FDIM + threadIdx.x];
    __syncthreads();
    if (c < NCLASS) {
        float s = bl2[c];
        for (int k = 0; k < FDIM; ++k) s = fmaf(zs[k], Wl2[(size_t)k * NCLASS + c], s);
        out[(size_t)g * NCLASS + c] = s;
    }
}

// ---------------- launch ----------------

extern "C" void kernel_launch(void* const* d_in, const int* in_sizes, int n_in,
                              void* d_out, int out_size, void* d_ws, size_t ws_size,
                              hipStream_t stream) {
    const float* x       = (const float*)d_in[0];
    const int*   ei      = (const int*)d_in[1];
    const int*   batch   = (const int*)d_in[2];
    const float* W1_rel  = (const float*)d_in[3];
    const float* b1_rel  = (const float*)d_in[4];
    const float* W1_root = (const float*)d_in[5];
    const float* Wc_rel  = (const float*)d_in[6];
    const float* bc_rel  = (const float*)d_in[7];
    const float* Wc_root = (const float*)d_in[8];
    const float* Wl1     = (const float*)d_in[9];
    const float* bl1     = (const float*)d_in[10];
    const float* Wl2     = (const float*)d_in[11];
    const float* bl2     = (const float*)d_in[12];
    float* out = (float*)d_out;

    const int* srcv = ei;            // edge_index[0]
    const int* dstv = ei + NEDGES;   // edge_index[1]

    char* ws = (char*)d_ws;
    size_t off = 0;
    auto alloc = [&](size_t bytes) -> void* {
        void* p = ws + off;
        off = (off + bytes + 255) & ~(size_t)255;
        return p;
    };
    u16* xb      = (u16*)alloc((size_t)NNODES * FDIM * 2);
    u16* hA      = (u16*)alloc((size_t)NNODES * FDIM * 2);
    u16* hB      = (u16*)alloc((size_t)NNODES * FDIM * 2);
    u16* Wcat    = (u16*)alloc((size_t)NLAYERS * 256 * FDIM * 2);
    int* csr     = (int*)alloc((size_t)NEDGES * 4);
    int* row_ptr = (int*)alloc((size_t)(NNODES + 1) * 4);
    int* degcur  = (int*)alloc((size_t)NNODES * 2 * 4);
    int* deg = degcur; int* cursor = degcur + NNODES;
    int* partial = (int*)alloc(4096);
    int* gptr    = (int*)alloc(1024);
    float* z     = (float*)alloc((size_t)NGRAPHS * NLAYERS * FDIM * 4);
    float* z2    = (float*)alloc((size_t)NGRAPHS * FDIM * 4);
    (void)ws_size; (void)in_sizes; (void)n_in; (void)out_size;

    hipMemsetAsync(degcur, 0, (size_t)NNODES * 2 * 4, stream);
    hipMemsetAsync(z, 0, (size_t)NGRAPHS * NLAYERS * FDIM * 4, stream);
    conv_x<<<(NNODES * FDIM / 4 + 255) / 256, 256, 0, stream>>>(x, xb);
    conv_w<<<(NLAYERS * 256 * FDIM + 255) / 256, 256, 0, stream>>>(W1_rel, W1_root, Wc_rel, Wc_root, Wcat);
    graph_ptr_kernel<<<1, 192, 0, stream>>>(batch, gptr);
    deg_kernel<<<(NEDGES + 255) / 256, 256, 0, stream>>>(dstv, deg);
    scan_partial<<<NB_SCAN, 256, 0, stream>>>(deg, partial);
    scan_prefix<<<1, 64, 0, stream>>>(partial);
    scan_final<<<NB_SCAN, 256, 0, stream>>>(deg, partial, row_ptr);
    fill_csr<<<(NEDGES + 255) / 256, 256, 0, stream>>>(srcv, dstv, row_ptr, cursor, csr);

    const int pool_nb = (NNODES + POOL_NPB - 1) / POOL_NPB;
    const u16* hin = xb;
    for (int l = 0; l < NLAYERS; ++l) {
        u16* hout = (l & 1) ? hB : hA;
        const u16* Wl = Wcat + (size_t)l * 256 * FDIM;
        const float* bb = (l == 0) ? b1_rel : bc_rel + (size_t)(l - 1) * FDIM;
        fused_layer<<<(NNODES + 127) / 128, 256, 0, stream>>>(hin, row_ptr, csr, Wl, bb, hout);
        pool_bf<<<pool_nb, 64, 0, stream>>>(hout, batch, z, l);
        hin = hout;
    }
    mlp1<<<NGRAPHS, 128, 0, stream>>>(z, gptr, Wl1, bl1, z2);
    mlp2<<<NGRAPHS, 128, 0, stream>>>(z2, Wl2, bl2, out);
}

// Round 5
// 724.291 us; speedup vs baseline: 1.5563x; 1.5563x over previous
//
#include <hip/hip_runtime.h>

#define NNODES 100000
#define NEDGES 1600000
#define FDIM 128
#define NGRAPHS 128
#define NLAYERS 4
#define NCLASS 10
#define NB_SCAN ((NNODES + 255) / 256)
#define POOL_NPB 128
#define LDA 40      // padded LDS row stride (elems): 80 B = 5*16 B -> 2-way bank alias (free)
#define LDC 136     // epilogue LDS row stride (elems): 272 B, 16B-aligned rows

typedef __attribute__((ext_vector_type(8))) short bf16x8;
typedef __attribute__((ext_vector_type(4))) float f32x4;
typedef unsigned short u16;
typedef unsigned int u32;

__device__ __forceinline__ u16 f2bf(float f) {
    u32 u = __float_as_uint(f);
    u += 0x7fffu + ((u >> 16) & 1u);   // round-to-nearest-even
    return (u16)(u >> 16);
}
__device__ __forceinline__ float bf_lo(u32 u) { return __uint_as_float(u << 16); }
__device__ __forceinline__ float bf_hi(u32 u) { return __uint_as_float(u & 0xffff0000u); }
__device__ __forceinline__ u32 pack_bf(float a, float b) {
    return (u32)f2bf(a) | ((u32)f2bf(b) << 16);
}

// ---------------- dtype conversion ----------------

__global__ __launch_bounds__(256) void conv_x(const float* __restrict__ x,
                                              u16* __restrict__ xb) {
    int i = (blockIdx.x * 256 + threadIdx.x) * 4;
    if (i < NNODES * FDIM) {
        float4 v = *(const float4*)(x + i);
        u32 p0 = pack_bf(v.x, v.y), p1 = pack_bf(v.z, v.w);
        *(u32*)(xb + i) = p0;
        *(u32*)(xb + i + 2) = p1;
    }
}

// Wcat[l][n][k]: k<128 -> Wrel[k][n], k>=128 -> Wroot[k-128][n]  (transposed, concat)
__global__ __launch_bounds__(256) void conv_w(const float* __restrict__ W1_rel,
                                              const float* __restrict__ W1_root,
                                              const float* __restrict__ Wc_rel,
                                              const float* __restrict__ Wc_root,
                                              u16* __restrict__ Wcat) {
    int idx = blockIdx.x * 256 + threadIdx.x;
    if (idx >= NLAYERS * 256 * FDIM) return;
    int n = idx & 127;
    int k = (idx >> 7) & 255;
    int l = idx >> 15;
    const float* Wr = (l == 0) ? W1_rel  : Wc_rel  + (size_t)(l - 1) * FDIM * FDIM;
    const float* Wt = (l == 0) ? W1_root : Wc_root + (size_t)(l - 1) * FDIM * FDIM;
    float v = (k < 128) ? Wr[(size_t)k * FDIM + n] : Wt[(size_t)(k - 128) * FDIM + n];
    Wcat[(size_t)l * 32768 + (size_t)n * 256 + k] = f2bf(v);
}

// ---------------- graph structure ----------------

__global__ __launch_bounds__(192) void graph_ptr_kernel(const int* __restrict__ batch,
                                                        int* __restrict__ gptr) {
    int g = threadIdx.x;
    if (g > NGRAPHS) return;
    int lo = 0, hi = NNODES;
    while (lo < hi) {
        int mid = (lo + hi) >> 1;
        if (batch[mid] < g) lo = mid + 1; else hi = mid;
    }
    gptr[g] = lo;
}

__global__ __launch_bounds__(256) void deg_kernel(const int* __restrict__ dst,
                                                  int* __restrict__ deg) {
    int e = blockIdx.x * 256 + threadIdx.x;
    if (e < NEDGES) atomicAdd(&deg[dst[e]], 1);
}

__global__ __launch_bounds__(256) void scan_partial(const int* __restrict__ deg,
                                                    int* __restrict__ partial) {
    __shared__ int sd[256];
    int i = blockIdx.x * 256 + threadIdx.x;
    sd[threadIdx.x] = (i < NNODES) ? deg[i] : 0;
    __syncthreads();
    for (int s = 128; s > 0; s >>= 1) {
        if (threadIdx.x < s) sd[threadIdx.x] += sd[threadIdx.x + s];
        __syncthreads();
    }
    if (threadIdx.x == 0) partial[blockIdx.x] = sd[0];
}

__global__ void scan_prefix(int* __restrict__ partial) {
    if (threadIdx.x == 0) {
        int run = 0;
        for (int b = 0; b < NB_SCAN; ++b) { int v = partial[b]; partial[b] = run; run += v; }
    }
}

__global__ __launch_bounds__(256) void scan_final(const int* __restrict__ deg,
                                                  const int* __restrict__ partial,
                                                  int* __restrict__ row_ptr) {
    __shared__ int sd[256];
    int i = blockIdx.x * 256 + threadIdx.x;
    int v = (i < NNODES) ? deg[i] : 0;
    sd[threadIdx.x] = v;
    __syncthreads();
    for (int s = 1; s < 256; s <<= 1) {
        int add = (threadIdx.x >= s) ? sd[threadIdx.x - s] : 0;
        __syncthreads();
        sd[threadIdx.x] += add;
        __syncthreads();
    }
    if (i < NNODES) {
        int excl = sd[threadIdx.x] - v + partial[blockIdx.x];
        row_ptr[i] = excl;
        if (i == NNODES - 1) row_ptr[NNODES] = excl + v;
    }
}

__global__ __launch_bounds__(256) void fill_csr(const int* __restrict__ src,
                                                const int* __restrict__ dst,
                                                const int* __restrict__ row_ptr,
                                                int* __restrict__ cursor,
                                                int* __restrict__ csr) {
    int e = blockIdx.x * 256 + threadIdx.x;
    if (e < NEDGES) {
        int d = dst[e];
        int p = atomicAdd(&cursor[d], 1);
        csr[row_ptr[d] + p] = src[e];
    }
}

// ---------------- aggregation (bf16 gather, fp32 accum): one wave per node, 8-deep MLP ----

__global__ __launch_bounds__(256) void agg_bf(const u16* __restrict__ h,
                                              const int* __restrict__ row_ptr,
                                              const int* __restrict__ csr,
                                              u16* __restrict__ agg) {
    int wave = threadIdx.x >> 6;
    int lane = threadIdx.x & 63;
    int node = (blockIdx.x << 2) + wave;
    if (node >= NNODES) return;
    int e0 = row_ptr[node], e1 = row_ptr[node + 1];
    float ax = 0.f, ay = 0.f;
    int e = e0;
    for (; e + 8 <= e1; e += 8) {
        int s0 = csr[e], s1 = csr[e + 1], s2 = csr[e + 2], s3 = csr[e + 3];
        int s4 = csr[e + 4], s5 = csr[e + 5], s6 = csr[e + 6], s7 = csr[e + 7];
        u32 v0 = ((const u32*)(h + (size_t)s0 * FDIM))[lane];
        u32 v1 = ((const u32*)(h + (size_t)s1 * FDIM))[lane];
        u32 v2 = ((const u32*)(h + (size_t)s2 * FDIM))[lane];
        u32 v3 = ((const u32*)(h + (size_t)s3 * FDIM))[lane];
        u32 v4 = ((const u32*)(h + (size_t)s4 * FDIM))[lane];
        u32 v5 = ((const u32*)(h + (size_t)s5 * FDIM))[lane];
        u32 v6 = ((const u32*)(h + (size_t)s6 * FDIM))[lane];
        u32 v7 = ((const u32*)(h + (size_t)s7 * FDIM))[lane];
        ax += bf_lo(v0) + bf_lo(v1) + bf_lo(v2) + bf_lo(v3)
            + bf_lo(v4) + bf_lo(v5) + bf_lo(v6) + bf_lo(v7);
        ay += bf_hi(v0) + bf_hi(v1) + bf_hi(v2) + bf_hi(v3)
            + bf_hi(v4) + bf_hi(v5) + bf_hi(v6) + bf_hi(v7);
    }
    for (; e + 2 <= e1; e += 2) {
        int s0 = csr[e], s1 = csr[e + 1];
        u32 v0 = ((const u32*)(h + (size_t)s0 * FDIM))[lane];
        u32 v1 = ((const u32*)(h + (size_t)s1 * FDIM))[lane];
        ax += bf_lo(v0) + bf_lo(v1);
        ay += bf_hi(v0) + bf_hi(v1);
    }
    if (e < e1) {
        int s0 = csr[e];
        u32 v0 = ((const u32*)(h + (size_t)s0 * FDIM))[lane];
        ax += bf_lo(v0); ay += bf_hi(v0);
    }
    ((u32*)(agg + (size_t)node * FDIM))[lane] = pack_bf(ax, ay);
}

// ---------------- MFMA GEMM: relu([agg|h] @ Wcat^T + b), bf16 in/out, fp32 accum ----------
// 128x128 tile, 4 waves (2x2), K=256 in 8 steps of 32. LDS union: Cs aliases As+Bs
// (34.8 KB total -> 4 blocks/CU; fragments live in registers across the final barrier).

__global__ __launch_bounds__(256) void gemm_mfma(const u16* __restrict__ aggb,
                                                 const u16* __restrict__ hinb,
                                                 const u16* __restrict__ Wl,   // [128 n][256 k]
                                                 const float* __restrict__ bias,
                                                 u16* __restrict__ houtb) {
    __shared__ u16 S[128 * LDC];        // 34816 B; As = S[0..5119], Bs = S[5120..10239], Cs = whole
    u16* As = S;
    u16* Bs = S + 128 * LDA;
    const int t = threadIdx.x;
    const int lane = t & 63;
    const int w = t >> 6;
    const int wr = w >> 1, wc = w & 1;
    const int row0 = blockIdx.x * 128;
    const int lr = lane & 15;
    const int lk = (lane >> 4) * 8;

    f32x4 acc[4][4];
#pragma unroll
    for (int m = 0; m < 4; ++m)
#pragma unroll
        for (int n = 0; n < 4; ++n) acc[m][n] = (f32x4){0.f, 0.f, 0.f, 0.f};

    for (int kb = 0; kb < 8; ++kb) {
        const u16* xsrc = (kb < 4) ? aggb : hinb;
        const int koff = (kb & 3) * 32;
        // stage A: 128 rows x 32 bf16 (512 chunks of 16 B)
#pragma unroll
        for (int it = 0; it < 2; ++it) {
            int u = it * 256 + t;
            int r = u >> 2, c = (u & 3) * 8;
            bf16x8 v = {};
            if (row0 + r < NNODES)
                v = *(const bf16x8*)(xsrc + (size_t)(row0 + r) * FDIM + koff + c);
            *(bf16x8*)&As[r * LDA + c] = v;
        }
        // stage B: 128 cols x 32 bf16
#pragma unroll
        for (int it = 0; it < 2; ++it) {
            int u = it * 256 + t;
            int r = u >> 2, c = (u & 3) * 8;
            bf16x8 v = *(const bf16x8*)(Wl + (size_t)r * 256 + kb * 32 + c);
            *(bf16x8*)&Bs[r * LDA + c] = v;
        }
        __syncthreads();
        bf16x8 a[4], b[4];
#pragma unroll
        for (int m = 0; m < 4; ++m)
            a[m] = *(const bf16x8*)&As[(wr * 64 + m * 16 + lr) * LDA + lk];
#pragma unroll
        for (int n = 0; n < 4; ++n)
            b[n] = *(const bf16x8*)&Bs[(wc * 64 + n * 16 + lr) * LDA + lk];
#pragma unroll
        for (int m = 0; m < 4; ++m)
#pragma unroll
            for (int n = 0; n < 4; ++n)
                acc[m][n] = __builtin_amdgcn_mfma_f32_16x16x32_bf16(a[m], b[n], acc[m][n], 0, 0, 0);
        __syncthreads();
    }
    // epilogue: bias + relu + bf16, repack via S (aliased Cs) for coalesced stores
#pragma unroll
    for (int m = 0; m < 4; ++m) {
#pragma unroll
        for (int n = 0; n < 4; ++n) {
            int col = wc * 64 + n * 16 + lr;
            float bb = bias[col];
#pragma unroll
            for (int reg = 0; reg < 4; ++reg) {
                int row = wr * 64 + m * 16 + (lane >> 4) * 4 + reg;
                float v = fmaxf(acc[m][n][reg] + bb, 0.f);
                S[row * LDC + col] = f2bf(v);
            }
        }
    }
    __syncthreads();
    {
        int r = t >> 1, half = t & 1;
        if (row0 + r < NNODES) {
#pragma unroll
            for (int j = 0; j < 8; ++j) {
                bf16x8 v = *(const bf16x8*)&S[r * LDC + half * 64 + j * 8];
                *(bf16x8*)(houtb + (size_t)(row0 + r) * FDIM + half * 64 + j * 8) = v;
            }
        }
    }
}

// ---------------- node-parallel mean pool (bf16 in, fp32 atomics; /count in mlp1) --------

__global__ __launch_bounds__(64) void pool_bf(const u16* __restrict__ h,
                                              const int* __restrict__ batch,
                                              float* __restrict__ z, int layer) {
    const int f2 = threadIdx.x;
    const int n0 = blockIdx.x * POOL_NPB;
    int n1 = n0 + POOL_NPB; if (n1 > NNODES) n1 = NNODES;
    __shared__ int bsh[POOL_NPB];
    for (int n = n0 + f2; n < n1; n += 64) bsh[n - n0] = batch[n];
    __syncthreads();
    float s0 = 0.f, s1 = 0.f;
    int g = bsh[0];
    for (int n = n0; n < n1; ++n) {
        int gn = bsh[n - n0];
        if (gn != g) {
            float* zp = &z[(size_t)g * (NLAYERS * FDIM) + layer * FDIM + 2 * f2];
            atomicAdd(zp, s0); atomicAdd(zp + 1, s1);
            s0 = 0.f; s1 = 0.f; g = gn;
        }
        u32 v = ((const u32*)(h + (size_t)n * FDIM))[f2];
        s0 += bf_lo(v); s1 += bf_hi(v);
    }
    float* zp = &z[(size_t)g * (NLAYERS * FDIM) + layer * FDIM + 2 * f2];
    atomicAdd(zp, s0); atomicAdd(zp + 1, s1);
}

// ---------------- final MLP (mean normalization folded into z load) ----------------

__global__ __launch_bounds__(128) void mlp1(const float* __restrict__ z,
                                            const int* __restrict__ gptr,
                                            const float* __restrict__ Wl1,
                                            const float* __restrict__ bl1,
                                            float* __restrict__ z2) {
    int g = blockIdx.x, j = threadIdx.x;
    __shared__ float zs[NLAYERS * FDIM];
    int cnt = gptr[g + 1] - gptr[g]; if (cnt < 1) cnt = 1;
    float invc = 1.0f / (float)cnt;
    for (int k = j; k < NLAYERS * FDIM; k += 128)
        zs[k] = z[(size_t)g * (NLAYERS * FDIM) + k] * invc;
    __syncthreads();
    float s = bl1[j];
    for (int k = 0; k < NLAYERS * FDIM; ++k) s = fmaf(zs[k], Wl1[(size_t)k * FDIM + j], s);
    z2[(size_t)g * FDIM + j] = fmaxf(s, 0.f);
}

__global__ __launch_bounds__(128) void mlp2(const float* __restrict__ z2,
                                            const float* __restrict__ Wl2,
                                            const float* __restrict__ bl2,
                                            float* __restrict__ out) {
    int g = blockIdx.x, c = threadIdx.x;
    __shared__ float zs[FDIM];
    if (threadIdx.x < FDIM) zs[threadIdx.x] = z2[(size_t)g * FDIM + threadIdx.x];
    __syncthreads();
    if (c < NCLASS) {
        float s = bl2[c];
        for (int k = 0; k < FDIM; ++k) s = fmaf(zs[k], Wl2[(size_t)k * NCLASS + c], s);
        out[(size_t)g * NCLASS + c] = s;
    }
}

// ---------------- launch ----------------

extern "C" void kernel_launch(void* const* d_in, const int* in_sizes, int n_in,
                              void* d_out, int out_size, void* d_ws, size_t ws_size,
                              hipStream_t stream) {
    const float* x       = (const float*)d_in[0];
    const int*   ei      = (const int*)d_in[1];
    const int*   batch   = (const int*)d_in[2];
    const float* W1_rel  = (const float*)d_in[3];
    const float* b1_rel  = (const float*)d_in[4];
    const float* W1_root = (const float*)d_in[5];
    const float* Wc_rel  = (const float*)d_in[6];
    const float* bc_rel  = (const float*)d_in[7];
    const float* Wc_root = (const float*)d_in[8];
    const float* Wl1     = (const float*)d_in[9];
    const float* bl1     = (const float*)d_in[10];
    const float* Wl2     = (const float*)d_in[11];
    const float* bl2     = (const float*)d_in[12];
    float* out = (float*)d_out;

    const int* srcv = ei;            // edge_index[0]
    const int* dstv = ei + NEDGES;   // edge_index[1]

    char* ws = (char*)d_ws;
    size_t off = 0;
    auto alloc = [&](size_t bytes) -> void* {
        void* p = ws + off;
        off = (off + bytes + 255) & ~(size_t)255;
        return p;
    };
    u16* xb      = (u16*)alloc((size_t)NNODES * FDIM * 2);
    u16* hA      = (u16*)alloc((size_t)NNODES * FDIM * 2);
    u16* hB      = (u16*)alloc((size_t)NNODES * FDIM * 2);
    u16* aggb    = (u16*)alloc((size_t)NNODES * FDIM * 2);
    u16* Wcat    = (u16*)alloc((size_t)NLAYERS * 256 * FDIM * 2);
    int* csr     = (int*)alloc((size_t)NEDGES * 4);
    int* row_ptr = (int*)alloc((size_t)(NNODES + 1) * 4);
    int* degcur  = (int*)alloc((size_t)NNODES * 2 * 4);
    int* deg = degcur; int* cursor = degcur + NNODES;
    int* partial = (int*)alloc(4096);
    int* gptr    = (int*)alloc(1024);
    float* z     = (float*)alloc((size_t)NGRAPHS * NLAYERS * FDIM * 4);
    float* z2    = (float*)alloc((size_t)NGRAPHS * FDIM * 4);
    (void)ws_size; (void)in_sizes; (void)n_in; (void)out_size;

    hipMemsetAsync(degcur, 0, (size_t)NNODES * 2 * 4, stream);
    hipMemsetAsync(z, 0, (size_t)NGRAPHS * NLAYERS * FDIM * 4, stream);
    conv_x<<<(NNODES * FDIM / 4 + 255) / 256, 256, 0, stream>>>(x, xb);
    conv_w<<<(NLAYERS * 256 * FDIM + 255) / 256, 256, 0, stream>>>(W1_rel, W1_root, Wc_rel, Wc_root, Wcat);
    graph_ptr_kernel<<<1, 192, 0, stream>>>(batch, gptr);
    deg_kernel<<<(NEDGES + 255) / 256, 256, 0, stream>>>(dstv, deg);
    scan_partial<<<NB_SCAN, 256, 0, stream>>>(deg, partial);
    scan_prefix<<<1, 64, 0, stream>>>(partial);
    scan_final<<<NB_SCAN, 256, 0, stream>>>(deg, partial, row_ptr);
    fill_csr<<<(NEDGES + 255) / 256, 256, 0, stream>>>(srcv, dstv, row_ptr, cursor, csr);

    const int pool_nb = (NNODES + POOL_NPB - 1) / POOL_NPB;
    const u16* hin = xb;
    for (int l = 0; l < NLAYERS; ++l) {
        u16* hout = (l & 1) ? hB : hA;
        const u16* Wl = Wcat + (size_t)l * 256 * FDIM;
        const float* bb = (l == 0) ? b1_rel : bc_rel + (size_t)(l - 1) * FDIM;
        agg_bf<<<(NNODES + 3) / 4, 256, 0, stream>>>(hin, row_ptr, csr, aggb);
        gemm_mfma<<<(NNODES + 127) / 128, 256, 0, stream>>>(aggb, hin, Wl, bb, hout);
        pool_bf<<<pool_nb, 64, 0, stream>>>(hout, batch, z, l);
        hin = hout;
    }
    mlp1<<<NGRAPHS, 128, 0, stream>>>(z, gptr, Wl1, bl1, z2);
    mlp2<<<NGRAPHS, 128, 0, stream>>>(z2, Wl2, bl2, out);
}

// Round 6
// 599.321 us; speedup vs baseline: 1.8809x; 1.2085x over previous
//
#include <hip/hip_runtime.h>

#define NNODES 100000
#define NEDGES 1600000
#define FDIM 128
#define NGRAPHS 128
#define NLAYERS 4
#define NCLASS 10
#define POOL_NPB 128
#define LDA 40      // padded LDS row stride (elems): 80 B = 5*16 B -> 2-way bank alias (free)
#define LDC 136     // epilogue LDS row stride (elems): 272 B, 16B-aligned rows
#define NBUCK 391   // buckets of 256 nodes: dst>>8, 391*256 = 100096 >= 100000
#define EPB 4096    // edges per block in build kernels
#define NBLK_E ((NEDGES + EPB - 1) / EPB)

typedef __attribute__((ext_vector_type(8))) short bf16x8;
typedef __attribute__((ext_vector_type(4))) float f32x4;
typedef unsigned short u16;
typedef unsigned int u32;
typedef unsigned long long u64;

__device__ __forceinline__ u16 f2bf(float f) {
    u32 u = __float_as_uint(f);
    u += 0x7fffu + ((u >> 16) & 1u);   // round-to-nearest-even
    return (u16)(u >> 16);
}
__device__ __forceinline__ float bf_lo(u32 u) { return __uint_as_float(u << 16); }
__device__ __forceinline__ float bf_hi(u32 u) { return __uint_as_float(u & 0xffff0000u); }
__device__ __forceinline__ u32 pack_bf(float a, float b) {
    return (u32)f2bf(a) | ((u32)f2bf(b) << 16);
}

// ---------------- dtype conversion ----------------

__global__ __launch_bounds__(256) void conv_x(const float* __restrict__ x,
                                              u16* __restrict__ xb) {
    int i = (blockIdx.x * 256 + threadIdx.x) * 4;
    if (i < NNODES * FDIM) {
        float4 v = *(const float4*)(x + i);
        u32 p0 = pack_bf(v.x, v.y), p1 = pack_bf(v.z, v.w);
        *(u32*)(xb + i) = p0;
        *(u32*)(xb + i + 2) = p1;
    }
}

// Wcat[l][n][k]: k<128 -> Wrel[k][n], k>=128 -> Wroot[k-128][n]  (transposed, concat)
__global__ __launch_bounds__(256) void conv_w(const float* __restrict__ W1_rel,
                                              const float* __restrict__ W1_root,
                                              const float* __restrict__ Wc_rel,
                                              const float* __restrict__ Wc_root,
                                              u16* __restrict__ Wcat) {
    int idx = blockIdx.x * 256 + threadIdx.x;
    if (idx >= NLAYERS * 256 * FDIM) return;
    int n = idx & 127;
    int k = (idx >> 7) & 255;
    int l = idx >> 15;
    const float* Wr = (l == 0) ? W1_rel  : Wc_rel  + (size_t)(l - 1) * FDIM * FDIM;
    const float* Wt = (l == 0) ? W1_root : Wc_root + (size_t)(l - 1) * FDIM * FDIM;
    float v = (k < 128) ? Wr[(size_t)k * FDIM + n] : Wt[(size_t)(k - 128) * FDIM + n];
    Wcat[(size_t)l * 32768 + (size_t)n * 256 + k] = f2bf(v);
}

// ---------------- graph structure: bucketed CSR build ----------------

__global__ __launch_bounds__(192) void graph_ptr_kernel(const int* __restrict__ batch,
                                                        int* __restrict__ gptr) {
    int g = threadIdx.x;
    if (g > NGRAPHS) return;
    int lo = 0, hi = NNODES;
    while (lo < hi) {
        int mid = (lo + hi) >> 1;
        if (batch[mid] < g) lo = mid + 1; else hi = mid;
    }
    gptr[g] = lo;
}

__global__ __launch_bounds__(256) void bucket_count(const int* __restrict__ dst,
                                                    int* __restrict__ bcount) {
    __shared__ int cnt[NBUCK];
    for (int i = threadIdx.x; i < NBUCK; i += 256) cnt[i] = 0;
    __syncthreads();
    int e0 = blockIdx.x * EPB;
    int e1 = e0 + EPB; if (e1 > NEDGES) e1 = NEDGES;
    for (int e = e0 + threadIdx.x; e < e1; e += 256)
        atomicAdd(&cnt[dst[e] >> 8], 1);
    __syncthreads();
    for (int i = threadIdx.x; i < NBUCK; i += 256)
        if (cnt[i]) atomicAdd(&bcount[i], cnt[i]);
}

__global__ __launch_bounds__(512) void bucket_scan(const int* __restrict__ bcount,
                                                   int* __restrict__ bbase,
                                                   int* __restrict__ bcur,
                                                   int* __restrict__ row_ptr) {
    __shared__ int sd[512];
    int t = threadIdx.x;
    int v = (t < NBUCK) ? bcount[t] : 0;
    sd[t] = v;
    __syncthreads();
    for (int s = 1; s < 512; s <<= 1) {
        int add = (t >= s) ? sd[t - s] : 0;
        __syncthreads();
        sd[t] += add;
        __syncthreads();
    }
    if (t < NBUCK) {
        int excl = sd[t] - v;
        bbase[t] = excl;
        bcur[t] = excl;
    }
    if (t == NBUCK - 1) {
        bbase[NBUCK] = sd[t];
        row_ptr[NNODES] = sd[t];
    }
}

// scatter packed (dst,src) records into per-bucket streams; LDS-aggregated reservations
__global__ __launch_bounds__(256) void bucket_scatter(const int* __restrict__ src,
                                                      const int* __restrict__ dst,
                                                      int* __restrict__ bcur,
                                                      u64* __restrict__ ebuf) {
    __shared__ int cnt[NBUCK];
    for (int i = threadIdx.x; i < NBUCK; i += 256) cnt[i] = 0;
    __syncthreads();
    int e0 = blockIdx.x * EPB;
    int e1 = e0 + EPB; if (e1 > NEDGES) e1 = NEDGES;
    for (int e = e0 + threadIdx.x; e < e1; e += 256)
        atomicAdd(&cnt[dst[e] >> 8], 1);
    __syncthreads();
    for (int i = threadIdx.x; i < NBUCK; i += 256) {
        int c = cnt[i];
        if (c) cnt[i] = atomicAdd(&bcur[i], c);   // cnt[i] becomes the block's base cursor
    }
    __syncthreads();
    for (int e = e0 + threadIdx.x; e < e1; e += 256) {
        int d = dst[e], s = src[e];
        int pos = atomicAdd(&cnt[d >> 8], 1);
        ebuf[pos] = ((u64)(u32)d << 32) | (u32)s;
    }
}

// one block per bucket: local count + scan -> row_ptr; scatter src into bucket's csr slice
__global__ __launch_bounds__(256) void bucket_csr(const u64* __restrict__ ebuf,
                                                  const int* __restrict__ bbase,
                                                  int* __restrict__ row_ptr,
                                                  int* __restrict__ csr) {
    __shared__ int cur[256];
    __shared__ int sd[256];
    int b = blockIdx.x, t = threadIdx.x;
    int ebase = bbase[b], eend = bbase[b + 1];
    int n0 = b << 8;
    cur[t] = 0;
    __syncthreads();
    for (int e = ebase + t; e < eend; e += 256) {
        int d = (int)(ebuf[e] >> 32);
        atomicAdd(&cur[d & 255], 1);
    }
    __syncthreads();
    int v = cur[t];
    sd[t] = v;
    __syncthreads();
    for (int s = 1; s < 256; s <<= 1) {
        int add = (t >= s) ? sd[t - s] : 0;
        __syncthreads();
        sd[t] += add;
        __syncthreads();
    }
    int excl = sd[t] - v;
    cur[t] = ebase + excl;
    if (n0 + t < NNODES) row_ptr[n0 + t] = ebase + excl;
    __syncthreads();
    for (int e = ebase + t; e < eend; e += 256) {
        u64 r = ebuf[e];
        int d = (int)(r >> 32);
        int pos = atomicAdd(&cur[d & 255], 1);
        csr[pos] = (int)(r & 0xffffffffu);
    }
}

// ---------------- aggregation (bf16 gather, fp32 accum): one wave per node, 8-deep MLP ----

__global__ __launch_bounds__(256) void agg_bf(const u16* __restrict__ h,
                                              const int* __restrict__ row_ptr,
                                              const int* __restrict__ csr,
                                              u16* __restrict__ agg) {
    int wave = threadIdx.x >> 6;
    int lane = threadIdx.x & 63;
    int node = (blockIdx.x << 2) + wave;
    if (node >= NNODES) return;
    int e0 = row_ptr[node], e1 = row_ptr[node + 1];
    float ax = 0.f, ay = 0.f;
    int e = e0;
    for (; e + 8 <= e1; e += 8) {
        int s0 = csr[e], s1 = csr[e + 1], s2 = csr[e + 2], s3 = csr[e + 3];
        int s4 = csr[e + 4], s5 = csr[e + 5], s6 = csr[e + 6], s7 = csr[e + 7];
        u32 v0 = ((const u32*)(h + (size_t)s0 * FDIM))[lane];
        u32 v1 = ((const u32*)(h + (size_t)s1 * FDIM))[lane];
        u32 v2 = ((const u32*)(h + (size_t)s2 * FDIM))[lane];
        u32 v3 = ((const u32*)(h + (size_t)s3 * FDIM))[lane];
        u32 v4 = ((const u32*)(h + (size_t)s4 * FDIM))[lane];
        u32 v5 = ((const u32*)(h + (size_t)s5 * FDIM))[lane];
        u32 v6 = ((const u32*)(h + (size_t)s6 * FDIM))[lane];
        u32 v7 = ((const u32*)(h + (size_t)s7 * FDIM))[lane];
        ax += bf_lo(v0) + bf_lo(v1) + bf_lo(v2) + bf_lo(v3)
            + bf_lo(v4) + bf_lo(v5) + bf_lo(v6) + bf_lo(v7);
        ay += bf_hi(v0) + bf_hi(v1) + bf_hi(v2) + bf_hi(v3)
            + bf_hi(v4) + bf_hi(v5) + bf_hi(v6) + bf_hi(v7);
    }
    for (; e + 2 <= e1; e += 2) {
        int s0 = csr[e], s1 = csr[e + 1];
        u32 v0 = ((const u32*)(h + (size_t)s0 * FDIM))[lane];
        u32 v1 = ((const u32*)(h + (size_t)s1 * FDIM))[lane];
        ax += bf_lo(v0) + bf_lo(v1);
        ay += bf_hi(v0) + bf_hi(v1);
    }
    if (e < e1) {
        int s0 = csr[e];
        u32 v0 = ((const u32*)(h + (size_t)s0 * FDIM))[lane];
        ax += bf_lo(v0); ay += bf_hi(v0);
    }
    ((u32*)(agg + (size_t)node * FDIM))[lane] = pack_bf(ax, ay);
}

// ---------------- MFMA GEMM: relu([agg|h] @ Wcat^T + b), bf16 in/out, fp32 accum ----------
// 128x128 tile, 4 waves (2x2), K=256 in 8 steps of 32. LDS union: Cs aliases As+Bs.

__global__ __launch_bounds__(256) void gemm_mfma(const u16* __restrict__ aggb,
                                                 const u16* __restrict__ hinb,
                                                 const u16* __restrict__ Wl,   // [128 n][256 k]
                                                 const float* __restrict__ bias,
                                                 u16* __restrict__ houtb) {
    __shared__ u16 S[128 * LDC];        // 34816 B; As = S[0..5119], Bs = S[5120..10239], Cs = whole
    u16* As = S;
    u16* Bs = S + 128 * LDA;
    const int t = threadIdx.x;
    const int lane = t & 63;
    const int w = t >> 6;
    const int wr = w >> 1, wc = w & 1;
    const int row0 = blockIdx.x * 128;
    const int lr = lane & 15;
    const int lk = (lane >> 4) * 8;

    f32x4 acc[4][4];
#pragma unroll
    for (int m = 0; m < 4; ++m)
#pragma unroll
        for (int n = 0; n < 4; ++n) acc[m][n] = (f32x4){0.f, 0.f, 0.f, 0.f};

    for (int kb = 0; kb < 8; ++kb) {
        const u16* xsrc = (kb < 4) ? aggb : hinb;
        const int koff = (kb & 3) * 32;
#pragma unroll
        for (int it = 0; it < 2; ++it) {
            int u = it * 256 + t;
            int r = u >> 2, c = (u & 3) * 8;
            bf16x8 v = {};
            if (row0 + r < NNODES)
                v = *(const bf16x8*)(xsrc + (size_t)(row0 + r) * FDIM + koff + c);
            *(bf16x8*)&As[r * LDA + c] = v;
        }
#pragma unroll
        for (int it = 0; it < 2; ++it) {
            int u = it * 256 + t;
            int r = u >> 2, c = (u & 3) * 8;
            bf16x8 v = *(const bf16x8*)(Wl + (size_t)r * 256 + kb * 32 + c);
            *(bf16x8*)&Bs[r * LDA + c] = v;
        }
        __syncthreads();
        bf16x8 a[4], b[4];
#pragma unroll
        for (int m = 0; m < 4; ++m)
            a[m] = *(const bf16x8*)&As[(wr * 64 + m * 16 + lr) * LDA + lk];
#pragma unroll
        for (int n = 0; n < 4; ++n)
            b[n] = *(const bf16x8*)&Bs[(wc * 64 + n * 16 + lr) * LDA + lk];
#pragma unroll
        for (int m = 0; m < 4; ++m)
#pragma unroll
            for (int n = 0; n < 4; ++n)
                acc[m][n] = __builtin_amdgcn_mfma_f32_16x16x32_bf16(a[m], b[n], acc[m][n], 0, 0, 0);
        __syncthreads();
    }
#pragma unroll
    for (int m = 0; m < 4; ++m) {
#pragma unroll
        for (int n = 0; n < 4; ++n) {
            int col = wc * 64 + n * 16 + lr;
            float bb = bias[col];
#pragma unroll
            for (int reg = 0; reg < 4; ++reg) {
                int row = wr * 64 + m * 16 + (lane >> 4) * 4 + reg;
                float v = fmaxf(acc[m][n][reg] + bb, 0.f);
                S[row * LDC + col] = f2bf(v);
            }
        }
    }
    __syncthreads();
    {
        int r = t >> 1, half = t & 1;
        if (row0 + r < NNODES) {
#pragma unroll
            for (int j = 0; j < 8; ++j) {
                bf16x8 v = *(const bf16x8*)&S[r * LDC + half * 64 + j * 8];
                *(bf16x8*)(houtb + (size_t)(row0 + r) * FDIM + half * 64 + j * 8) = v;
            }
        }
    }
}

// ---------------- node-parallel mean pool (bf16 in, fp32 atomics; /count in mlp1) --------

__global__ __launch_bounds__(64) void pool_bf(const u16* __restrict__ h,
                                              const int* __restrict__ batch,
                                              float* __restrict__ z, int layer) {
    const int f2 = threadIdx.x;
    const int n0 = blockIdx.x * POOL_NPB;
    int n1 = n0 + POOL_NPB; if (n1 > NNODES) n1 = NNODES;
    __shared__ int bsh[POOL_NPB];
    for (int n = n0 + f2; n < n1; n += 64) bsh[n - n0] = batch[n];
    __syncthreads();
    float s0 = 0.f, s1 = 0.f;
    int g = bsh[0];
    for (int n = n0; n < n1; ++n) {
        int gn = bsh[n - n0];
        if (gn != g) {
            float* zp = &z[(size_t)g * (NLAYERS * FDIM) + layer * FDIM + 2 * f2];
            atomicAdd(zp, s0); atomicAdd(zp + 1, s1);
            s0 = 0.f; s1 = 0.f; g = gn;
        }
        u32 v = ((const u32*)(h + (size_t)n * FDIM))[f2];
        s0 += bf_lo(v); s1 += bf_hi(v);
    }
    float* zp = &z[(size_t)g * (NLAYERS * FDIM) + layer * FDIM + 2 * f2];
    atomicAdd(zp, s0); atomicAdd(zp + 1, s1);
}

// ---------------- final MLP (mean normalization folded into z load) ----------------

__global__ __launch_bounds__(128) void mlp1(const float* __restrict__ z,
                                            const int* __restrict__ gptr,
                                            const float* __restrict__ Wl1,
                                            const float* __restrict__ bl1,
                                            float* __restrict__ z2) {
    int g = blockIdx.x, j = threadIdx.x;
    __shared__ float zs[NLAYERS * FDIM];
    int cnt = gptr[g + 1] - gptr[g]; if (cnt < 1) cnt = 1;
    float invc = 1.0f / (float)cnt;
    for (int k = j; k < NLAYERS * FDIM; k += 128)
        zs[k] = z[(size_t)g * (NLAYERS * FDIM) + k] * invc;
    __syncthreads();
    float s = bl1[j];
    for (int k = 0; k < NLAYERS * FDIM; ++k) s = fmaf(zs[k], Wl1[(size_t)k * FDIM + j], s);
    z2[(size_t)g * FDIM + j] = fmaxf(s, 0.f);
}

__global__ __launch_bounds__(128) void mlp2(const float* __restrict__ z2,
                                            const float* __restrict__ Wl2,
                                            const float* __restrict__ bl2,
                                            float* __restrict__ out) {
    int g = blockIdx.x, c = threadIdx.x;
    __shared__ float zs[FDIM];
    if (threadIdx.x < FDIM) zs[threadIdx.x] = z2[(size_t)g * FDIM + threadIdx.x];
    __syncthreads();
    if (c < NCLASS) {
        float s = bl2[c];
        for (int k = 0; k < FDIM; ++k) s = fmaf(zs[k], Wl2[(size_t)k * NCLASS + c], s);
        out[(size_t)g * NCLASS + c] = s;
    }
}

// ---------------- launch ----------------

extern "C" void kernel_launch(void* const* d_in, const int* in_sizes, int n_in,
                              void* d_out, int out_size, void* d_ws, size_t ws_size,
                              hipStream_t stream) {
    const float* x       = (const float*)d_in[0];
    const int*   ei      = (const int*)d_in[1];
    const int*   batch   = (const int*)d_in[2];
    const float* W1_rel  = (const float*)d_in[3];
    const float* b1_rel  = (const float*)d_in[4];
    const float* W1_root = (const float*)d_in[5];
    const float* Wc_rel  = (const float*)d_in[6];
    const float* bc_rel  = (const float*)d_in[7];
    const float* Wc_root = (const float*)d_in[8];
    const float* Wl1     = (const float*)d_in[9];
    const float* bl1     = (const float*)d_in[10];
    const float* Wl2     = (const float*)d_in[11];
    const float* bl2     = (const float*)d_in[12];
    float* out = (float*)d_out;

    const int* srcv = ei;            // edge_index[0]
    const int* dstv = ei + NEDGES;   // edge_index[1]

    char* ws = (char*)d_ws;
    size_t off = 0;
    auto alloc = [&](size_t bytes) -> void* {
        void* p = ws + off;
        off = (off + bytes + 255) & ~(size_t)255;
        return p;
    };
    u16* xb      = (u16*)alloc((size_t)NNODES * FDIM * 2);
    u16* hA      = (u16*)alloc((size_t)NNODES * FDIM * 2);
    u16* hB      = (u16*)alloc((size_t)NNODES * FDIM * 2);
    u16* aggb    = (u16*)alloc((size_t)NNODES * FDIM * 2);
    u16* Wcat    = (u16*)alloc((size_t)NLAYERS * 256 * FDIM * 2);
    u64* ebuf    = (u64*)alloc((size_t)NEDGES * 8);
    int* csr     = (int*)alloc((size_t)NEDGES * 4);
    int* row_ptr = (int*)alloc((size_t)(NNODES + 1) * 4);
    int* bcount  = (int*)alloc((size_t)(NBUCK + 1) * 4);
    int* bbase   = (int*)alloc((size_t)(NBUCK + 1) * 4);
    int* bcur    = (int*)alloc((size_t)(NBUCK + 1) * 4);
    int* gptr    = (int*)alloc(1024);
    float* z     = (float*)alloc((size_t)NGRAPHS * NLAYERS * FDIM * 4);
    float* z2    = (float*)alloc((size_t)NGRAPHS * FDIM * 4);
    (void)ws_size; (void)in_sizes; (void)n_in; (void)out_size;

    hipMemsetAsync(bcount, 0, (size_t)(NBUCK + 1) * 4, stream);
    hipMemsetAsync(z, 0, (size_t)NGRAPHS * NLAYERS * FDIM * 4, stream);
    conv_x<<<(NNODES * FDIM / 4 + 255) / 256, 256, 0, stream>>>(x, xb);
    conv_w<<<(NLAYERS * 256 * FDIM + 255) / 256, 256, 0, stream>>>(W1_rel, W1_root, Wc_rel, Wc_root, Wcat);
    graph_ptr_kernel<<<1, 192, 0, stream>>>(batch, gptr);
    bucket_count<<<NBLK_E, 256, 0, stream>>>(dstv, bcount);
    bucket_scan<<<1, 512, 0, stream>>>(bcount, bbase, bcur, row_ptr);
    bucket_scatter<<<NBLK_E, 256, 0, stream>>>(srcv, dstv, bcur, ebuf);
    bucket_csr<<<NBUCK, 256, 0, stream>>>(ebuf, bbase, row_ptr, csr);

    const int pool_nb = (NNODES + POOL_NPB - 1) / POOL_NPB;
    const u16* hin = xb;
    for (int l = 0; l < NLAYERS; ++l) {
        u16* hout = (l & 1) ? hB : hA;
        const u16* Wl = Wcat + (size_t)l * 256 * FDIM;
        const float* bb = (l == 0) ? b1_rel : bc_rel + (size_t)(l - 1) * FDIM;
        agg_bf<<<(NNODES + 3) / 4, 256, 0, stream>>>(hin, row_ptr, csr, aggb);
        gemm_mfma<<<(NNODES + 127) / 128, 256, 0, stream>>>(aggb, hin, Wl, bb, hout);
        pool_bf<<<pool_nb, 64, 0, stream>>>(hout, batch, z, l);
        hin = hout;
    }
    mlp1<<<NGRAPHS, 128, 0, stream>>>(z, gptr, Wl1, bl1, z2);
    mlp2<<<NGRAPHS, 128, 0, stream>>>(z2, Wl2, bl2, out);
}

// Round 8
// 464.300 us; speedup vs baseline: 2.4278x; 1.2908x over previous
//
#include <hip/hip_runtime.h>

#define NNODES 100000
#define NEDGES 1600000
#define FDIM 128
#define NGRAPHS 128
#define NLAYERS 4
#define NCLASS 10
#define LDA 40      // padded LDS row stride (elems): 80 B = 5*16 B -> 2-way bank alias (free)
#define LDC 136     // epilogue LDS row stride (elems): 272 B, 16B-aligned rows
#define NBUCK 391   // buckets of 256 nodes: dst>>8, 391*256 = 100096 >= 100000
#define EPB 4096    // edges per block in build kernels
#define NBLK_E ((NEDGES + EPB - 1) / EPB)

typedef __attribute__((ext_vector_type(8))) short bf16x8;
typedef __attribute__((ext_vector_type(4))) float f32x4;
typedef unsigned short u16;
typedef unsigned int u32;
typedef unsigned long long u64;

__device__ __forceinline__ u16 f2bf(float f) {
    u32 u = __float_as_uint(f);
    u += 0x7fffu + ((u >> 16) & 1u);   // round-to-nearest-even
    return (u16)(u >> 16);
}
__device__ __forceinline__ float bf_lo(u32 u) { return __uint_as_float(u << 16); }
__device__ __forceinline__ float bf_hi(u32 u) { return __uint_as_float(u & 0xffff0000u); }
__device__ __forceinline__ u32 pack_bf(float a, float b) {
    return (u32)f2bf(a) | ((u32)f2bf(b) << 16);
}

// ---------------- dtype conversion ----------------

__global__ __launch_bounds__(256) void conv_x(const float* __restrict__ x,
                                              u16* __restrict__ xb) {
    int i = (blockIdx.x * 256 + threadIdx.x) * 4;
    if (i < NNODES * FDIM) {
        float4 v = *(const float4*)(x + i);
        u32 p0 = pack_bf(v.x, v.y), p1 = pack_bf(v.z, v.w);
        *(u32*)(xb + i) = p0;
        *(u32*)(xb + i + 2) = p1;
    }
}

// Wcat[l][n][k]: k<128 -> Wrel[k][n], k>=128 -> Wroot[k-128][n]  (transposed, concat)
__global__ __launch_bounds__(256) void conv_w(const float* __restrict__ W1_rel,
                                              const float* __restrict__ W1_root,
                                              const float* __restrict__ Wc_rel,
                                              const float* __restrict__ Wc_root,
                                              u16* __restrict__ Wcat) {
    int idx = blockIdx.x * 256 + threadIdx.x;
    if (idx >= NLAYERS * 256 * FDIM) return;
    int n = idx & 127;
    int k = (idx >> 7) & 255;
    int l = idx >> 15;
    const float* Wr = (l == 0) ? W1_rel  : Wc_rel  + (size_t)(l - 1) * FDIM * FDIM;
    const float* Wt = (l == 0) ? W1_root : Wc_root + (size_t)(l - 1) * FDIM * FDIM;
    float v = (k < 128) ? Wr[(size_t)k * FDIM + n] : Wt[(size_t)(k - 128) * FDIM + n];
    Wcat[(size_t)l * 32768 + (size_t)n * 256 + k] = f2bf(v);
}

// ---------------- graph structure: bucketed CSR build ----------------

__global__ __launch_bounds__(192) void graph_ptr_kernel(const int* __restrict__ batch,
                                                        int* __restrict__ gptr) {
    int g = threadIdx.x;
    if (g > NGRAPHS) return;
    int lo = 0, hi = NNODES;
    while (lo < hi) {
        int mid = (lo + hi) >> 1;
        if (batch[mid] < g) lo = mid + 1; else hi = mid;
    }
    gptr[g] = lo;
}

__global__ __launch_bounds__(256) void bucket_count(const int* __restrict__ dst,
                                                    int* __restrict__ bcount) {
    __shared__ int cnt[NBUCK];
    for (int i = threadIdx.x; i < NBUCK; i += 256) cnt[i] = 0;
    __syncthreads();
    int e0 = blockIdx.x * EPB;
    int e1 = e0 + EPB; if (e1 > NEDGES) e1 = NEDGES;
    for (int e = e0 + threadIdx.x; e < e1; e += 256)
        atomicAdd(&cnt[dst[e] >> 8], 1);
    __syncthreads();
    for (int i = threadIdx.x; i < NBUCK; i += 256)
        if (cnt[i]) atomicAdd(&bcount[i], cnt[i]);
}

__global__ __launch_bounds__(512) void bucket_scan(const int* __restrict__ bcount,
                                                   int* __restrict__ bbase,
                                                   int* __restrict__ bcur,
                                                   int* __restrict__ row_ptr) {
    __shared__ int sd[512];
    int t = threadIdx.x;
    int v = (t < NBUCK) ? bcount[t] : 0;
    sd[t] = v;
    __syncthreads();
    for (int s = 1; s < 512; s <<= 1) {
        int add = (t >= s) ? sd[t - s] : 0;
        __syncthreads();
        sd[t] += add;
        __syncthreads();
    }
    if (t < NBUCK) {
        int excl = sd[t] - v;
        bbase[t] = excl;
        bcur[t] = excl;
    }
    if (t == NBUCK - 1) {
        bbase[NBUCK] = sd[t];
        row_ptr[NNODES] = sd[t];
    }
}

// scatter packed (dst,src) records into per-bucket streams; LDS-aggregated reservations
__global__ __launch_bounds__(256) void bucket_scatter(const int* __restrict__ src,
                                                      const int* __restrict__ dst,
                                                      int* __restrict__ bcur,
                                                      u64* __restrict__ ebuf) {
    __shared__ int cnt[NBUCK];
    for (int i = threadIdx.x; i < NBUCK; i += 256) cnt[i] = 0;
    __syncthreads();
    int e0 = blockIdx.x * EPB;
    int e1 = e0 + EPB; if (e1 > NEDGES) e1 = NEDGES;
    for (int e = e0 + threadIdx.x; e < e1; e += 256)
        atomicAdd(&cnt[dst[e] >> 8], 1);
    __syncthreads();
    for (int i = threadIdx.x; i < NBUCK; i += 256) {
        int c = cnt[i];
        if (c) cnt[i] = atomicAdd(&bcur[i], c);   // cnt[i] becomes the block's base cursor
    }
    __syncthreads();
    for (int e = e0 + threadIdx.x; e < e1; e += 256) {
        int d = dst[e], s = src[e];
        int pos = atomicAdd(&cnt[d >> 8], 1);
        ebuf[pos] = ((u64)(u32)d << 32) | (u32)s;
    }
}

// one block per bucket: local count + scan -> row_ptr; scatter src into bucket's csr slice
__global__ __launch_bounds__(256) void bucket_csr(const u64* __restrict__ ebuf,
                                                  const int* __restrict__ bbase,
                                                  int* __restrict__ row_ptr,
                                                  int* __restrict__ csr) {
    __shared__ int cur[256];
    __shared__ int sd[256];
    int b = blockIdx.x, t = threadIdx.x;
    int ebase = bbase[b], eend = bbase[b + 1];
    int n0 = b << 8;
    cur[t] = 0;
    __syncthreads();
    for (int e = ebase + t; e < eend; e += 256) {
        int d = (int)(ebuf[e] >> 32);
        atomicAdd(&cur[d & 255], 1);
    }
    __syncthreads();
    int v = cur[t];
    sd[t] = v;
    __syncthreads();
    for (int s = 1; s < 256; s <<= 1) {
        int add = (t >= s) ? sd[t - s] : 0;
        __syncthreads();
        sd[t] += add;
        __syncthreads();
    }
    int excl = sd[t] - v;
    cur[t] = ebase + excl;
    if (n0 + t < NNODES) row_ptr[n0 + t] = ebase + excl;
    __syncthreads();
    for (int e = ebase + t; e < eend; e += 256) {
        u64 r = ebuf[e];
        int d = (int)(r >> 32);
        int pos = atomicAdd(&cur[d & 255], 1);
        csr[pos] = (int)(r & 0xffffffffu);
    }
}

// ---------------- aggregation: one wave per node, scalar-indexed gather ----------------
// node is wave-uniform: load all indices with ONE coalesced per-lane load, broadcast via
// readlane (SGPR base addressing, SALU addr math), 16 row loads in flight per batch.

__global__ __launch_bounds__(256) void agg_bf(const u16* __restrict__ h,
                                              const int* __restrict__ row_ptr,
                                              const int* __restrict__ csr,
                                              u16* __restrict__ agg) {
    int wave = threadIdx.x >> 6;
    int lane = threadIdx.x & 63;
    int node = (blockIdx.x << 2) + wave;
    if (node >= NNODES) return;
    int e0 = row_ptr[node], e1 = row_ptr[node + 1];
    int cnt = e1 - e0;
    float ax = 0.f, ay = 0.f;
    if (cnt <= 64) {
        int myidx = (lane < cnt) ? csr[e0 + lane] : 0;
        int nb = (cnt + 15) >> 4;
        for (int b = 0; b < nb; ++b) {
            int base = b * 16;
            u32 vv[16];
#pragma unroll
            for (int i = 0; i < 16; ++i) {
                int s = __builtin_amdgcn_readlane(myidx, base + i);
                vv[i] = ((const u32*)(h + (size_t)s * FDIM))[lane];
            }
            if (base + 16 <= cnt) {
#pragma unroll
                for (int i = 0; i < 16; ++i) { ax += bf_lo(vv[i]); ay += bf_hi(vv[i]); }
            } else {
#pragma unroll
                for (int i = 0; i < 16; ++i) {
                    float m = (base + i < cnt) ? 1.f : 0.f;
                    ax = fmaf(bf_lo(vv[i]), m, ax);
                    ay = fmaf(bf_hi(vv[i]), m, ay);
                }
            }
        }
    } else {
        int e = e0;
        for (; e + 8 <= e1; e += 8) {
            int s0 = csr[e], s1 = csr[e + 1], s2 = csr[e + 2], s3 = csr[e + 3];
            int s4 = csr[e + 4], s5 = csr[e + 5], s6 = csr[e + 6], s7 = csr[e + 7];
            u32 v0 = ((const u32*)(h + (size_t)s0 * FDIM))[lane];
            u32 v1 = ((const u32*)(h + (size_t)s1 * FDIM))[lane];
            u32 v2 = ((const u32*)(h + (size_t)s2 * FDIM))[lane];
            u32 v3 = ((const u32*)(h + (size_t)s3 * FDIM))[lane];
            u32 v4 = ((const u32*)(h + (size_t)s4 * FDIM))[lane];
            u32 v5 = ((const u32*)(h + (size_t)s5 * FDIM))[lane];
            u32 v6 = ((const u32*)(h + (size_t)s6 * FDIM))[lane];
            u32 v7 = ((const u32*)(h + (size_t)s7 * FDIM))[lane];
            ax += bf_lo(v0) + bf_lo(v1) + bf_lo(v2) + bf_lo(v3)
                + bf_lo(v4) + bf_lo(v5) + bf_lo(v6) + bf_lo(v7);
            ay += bf_hi(v0) + bf_hi(v1) + bf_hi(v2) + bf_hi(v3)
                + bf_hi(v4) + bf_hi(v5) + bf_hi(v6) + bf_hi(v7);
        }
        for (; e < e1; ++e) {
            int s0 = csr[e];
            u32 v0 = ((const u32*)(h + (size_t)s0 * FDIM))[lane];
            ax += bf_lo(v0); ay += bf_hi(v0);
        }
    }
    ((u32*)(agg + (size_t)node * FDIM))[lane] = pack_bf(ax, ay);
}

// ---------------- MFMA GEMM + fused mean-pool epilogue ----------------
// relu([agg|h] @ Wcat^T + b) -> hout (bf16), and per-graph sums of the tile into z.
// 128x128 tile, 4 waves (2x2), K=256 in 8 steps of 32. LDS union: Cs aliases As+Bs.

__global__ __launch_bounds__(256) void gemm_mfma(const u16* __restrict__ aggb,
                                                 const u16* __restrict__ hinb,
                                                 const u16* __restrict__ Wl,   // [128 n][256 k]
                                                 const float* __restrict__ bias,
                                                 const int* __restrict__ batch,
                                                 float* __restrict__ z, int layer,
                                                 u16* __restrict__ houtb) {
    __shared__ u16 S[128 * LDC];        // 34816 B; As = S[0..5119], Bs = S[5120..10239], Cs = whole
    __shared__ int batchs[128];
    u16* As = S;
    u16* Bs = S + 128 * LDA;
    const int t = threadIdx.x;
    const int lane = t & 63;
    const int w = t >> 6;
    const int wr = w >> 1, wc = w & 1;
    const int row0 = blockIdx.x * 128;
    const int lr = lane & 15;
    const int lk = (lane >> 4) * 8;

    f32x4 acc[4][4];
#pragma unroll
    for (int m = 0; m < 4; ++m)
#pragma unroll
        for (int n = 0; n < 4; ++n) acc[m][n] = (f32x4){0.f, 0.f, 0.f, 0.f};

    for (int kb = 0; kb < 8; ++kb) {
        const u16* xsrc = (kb < 4) ? aggb : hinb;
        const int koff = (kb & 3) * 32;
#pragma unroll
        for (int it = 0; it < 2; ++it) {
            int u = it * 256 + t;
            int r = u >> 2, c = (u & 3) * 8;
            bf16x8 v = {};
            if (row0 + r < NNODES)
                v = *(const bf16x8*)(xsrc + (size_t)(row0 + r) * FDIM + koff + c);
            *(bf16x8*)&As[r * LDA + c] = v;
        }
#pragma unroll
        for (int it = 0; it < 2; ++it) {
            int u = it * 256 + t;
            int r = u >> 2, c = (u & 3) * 8;
            bf16x8 v = *(const bf16x8*)(Wl + (size_t)r * 256 + kb * 32 + c);
            *(bf16x8*)&Bs[r * LDA + c] = v;
        }
        __syncthreads();
        bf16x8 a[4], b[4];
#pragma unroll
        for (int m = 0; m < 4; ++m)
            a[m] = *(const bf16x8*)&As[(wr * 64 + m * 16 + lr) * LDA + lk];
#pragma unroll
        for (int n = 0; n < 4; ++n)
            b[n] = *(const bf16x8*)&Bs[(wc * 64 + n * 16 + lr) * LDA + lk];
#pragma unroll
        for (int m = 0; m < 4; ++m)
#pragma unroll
            for (int n = 0; n < 4; ++n)
                acc[m][n] = __builtin_amdgcn_mfma_f32_16x16x32_bf16(a[m], b[n], acc[m][n], 0, 0, 0);
        __syncthreads();
    }
    // epilogue: bias + relu + bf16, repack via S (aliased Cs)
#pragma unroll
    for (int m = 0; m < 4; ++m) {
#pragma unroll
        for (int n = 0; n < 4; ++n) {
            int col = wc * 64 + n * 16 + lr;
            float bb = bias[col];
#pragma unroll
            for (int reg = 0; reg < 4; ++reg) {
                int row = wr * 64 + m * 16 + (lane >> 4) * 4 + reg;
                float v = fmaxf(acc[m][n][reg] + bb, 0.f);
                S[row * LDC + col] = f2bf(v);
            }
        }
    }
    if (t < 128) batchs[t] = (row0 + t < NNODES) ? batch[row0 + t] : NGRAPHS;
    __syncthreads();
    // coalesced global store
    {
        int r = t >> 1, half = t & 1;
        if (row0 + r < NNODES) {
#pragma unroll
            for (int j = 0; j < 8; ++j) {
                bf16x8 v = *(const bf16x8*)&S[r * LDC + half * 64 + j * 8];
                *(bf16x8*)(houtb + (size_t)(row0 + r) * FDIM + half * 64 + j * 8) = v;
            }
        }
    }
    // fused pool: 2 threads per column, run-length sums + boundary atomics
    {
        int col = t & 127, half = t >> 7;
        int r0 = half * 64, r1 = r0 + 64;
        float* zl = z + (size_t)layer * FDIM + col;
        int g = batchs[r0];
        float s = 0.f;
        for (int r = r0; r < r1; ++r) {
            int gn = batchs[r];
            if (gn != g) {
                atomicAdd(zl + (size_t)g * (NLAYERS * FDIM), s);
                s = 0.f; g = gn;
            }
            s += __uint_as_float((u32)S[r * LDC + col] << 16);   // bf16 -> f32 (single shift)
        }
        atomicAdd(zl + (size_t)g * (NLAYERS * FDIM), s);
    }
}

// ---------------- final MLP (mean normalization folded into z load) ----------------

__global__ __launch_bounds__(128) void mlp1(const float* __restrict__ z,
                                            const int* __restrict__ gptr,
                                            const float* __restrict__ Wl1,
                                            const float* __restrict__ bl1,
                                            float* __restrict__ z2) {
    int g = blockIdx.x, j = threadIdx.x;
    __shared__ float zs[NLAYERS * FDIM];
    int cnt = gptr[g + 1] - gptr[g]; if (cnt < 1) cnt = 1;
    float invc = 1.0f / (float)cnt;
    for (int k = j; k < NLAYERS * FDIM; k += 128)
        zs[k] = z[(size_t)g * (NLAYERS * FDIM) + k] * invc;
    __syncthreads();
    float s = bl1[j];
    for (int k = 0; k < NLAYERS * FDIM; ++k) s = fmaf(zs[k], Wl1[(size_t)k * FDIM + j], s);
    z2[(size_t)g * FDIM + j] = fmaxf(s, 0.f);
}

__global__ __launch_bounds__(128) void mlp2(const float* __restrict__ z2,
                                            const float* __restrict__ Wl2,
                                            const float* __restrict__ bl2,
                                            float* __restrict__ out) {
    int g = blockIdx.x, c = threadIdx.x;
    __shared__ float zs[FDIM];
    if (threadIdx.x < FDIM) zs[threadIdx.x] = z2[(size_t)g * FDIM + threadIdx.x];
    __syncthreads();
    if (c < NCLASS) {
        float s = bl2[c];
        for (int k = 0; k < FDIM; ++k) s = fmaf(zs[k], Wl2[(size_t)k * NCLASS + c], s);
        out[(size_t)g * NCLASS + c] = s;
    }
}

// ---------------- launch ----------------

extern "C" void kernel_launch(void* const* d_in, const int* in_sizes, int n_in,
                              void* d_out, int out_size, void* d_ws, size_t ws_size,
                              hipStream_t stream) {
    const float* x       = (const float*)d_in[0];
    const int*   ei      = (const int*)d_in[1];
    const int*   batch   = (const int*)d_in[2];
    const float* W1_rel  = (const float*)d_in[3];
    const float* b1_rel  = (const float*)d_in[4];
    const float* W1_root = (const float*)d_in[5];
    const float* Wc_rel  = (const float*)d_in[6];
    const float* bc_rel  = (const float*)d_in[7];
    const float* Wc_root = (const float*)d_in[8];
    const float* Wl1     = (const float*)d_in[9];
    const float* bl1     = (const float*)d_in[10];
    const float* Wl2     = (const float*)d_in[11];
    const float* bl2     = (const float*)d_in[12];
    float* out = (float*)d_out;

    const int* srcv = ei;            // edge_index[0]
    const int* dstv = ei + NEDGES;   // edge_index[1]

    char* ws = (char*)d_ws;
    size_t off = 0;
    auto alloc = [&](size_t bytes) -> void* {
        void* p = ws + off;
        off = (off + bytes + 255) & ~(size_t)255;
        return p;
    };
    u16* xb      = (u16*)alloc((size_t)NNODES * FDIM * 2);
    u16* hA      = (u16*)alloc((size_t)NNODES * FDIM * 2);
    u16* hB      = (u16*)alloc((size_t)NNODES * FDIM * 2);
    u16* aggb    = (u16*)alloc((size_t)NNODES * FDIM * 2);
    u16* Wcat    = (u16*)alloc((size_t)NLAYERS * 256 * FDIM * 2);
    u64* ebuf    = (u64*)alloc((size_t)NEDGES * 8);
    int* csr     = (int*)alloc((size_t)NEDGES * 4);
    int* row_ptr = (int*)alloc((size_t)(NNODES + 1) * 4);
    int* bcount  = (int*)alloc((size_t)(NBUCK + 1) * 4);
    int* bbase   = (int*)alloc((size_t)(NBUCK + 1) * 4);
    int* bcur    = (int*)alloc((size_t)(NBUCK + 1) * 4);
    int* gptr    = (int*)alloc(1024);
    float* z     = (float*)alloc((size_t)(NGRAPHS + 1) * NLAYERS * FDIM * 4);
    float* z2    = (float*)alloc((size_t)NGRAPHS * FDIM * 4);
    (void)ws_size; (void)in_sizes; (void)n_in; (void)out_size;

    hipMemsetAsync(bcount, 0, (size_t)(NBUCK + 1) * 4, stream);
    hipMemsetAsync(z, 0, (size_t)(NGRAPHS + 1) * NLAYERS * FDIM * 4, stream);
    conv_x<<<(NNODES * FDIM / 4 + 255) / 256, 256, 0, stream>>>(x, xb);
    conv_w<<<(NLAYERS * 256 * FDIM + 255) / 256, 256, 0, stream>>>(W1_rel, W1_root, Wc_rel, Wc_root, Wcat);
    graph_ptr_kernel<<<1, 192, 0, stream>>>(batch, gptr);
    bucket_count<<<NBLK_E, 256, 0, stream>>>(dstv, bcount);
    bucket_scan<<<1, 512, 0, stream>>>(bcount, bbase, bcur, row_ptr);
    bucket_scatter<<<NBLK_E, 256, 0, stream>>>(srcv, dstv, bcur, ebuf);
    bucket_csr<<<NBUCK, 256, 0, stream>>>(ebuf, bbase, row_ptr, csr);

    const u16* hin = xb;
    for (int l = 0; l < NLAYERS; ++l) {
        u16* hout = (l & 1) ? hB : hA;
        const u16* Wl = Wcat + (size_t)l * 256 * FDIM;
        const float* bb = (l == 0) ? b1_rel : bc_rel + (size_t)(l - 1) * FDIM;
        agg_bf<<<(NNODES + 3) / 4, 256, 0, stream>>>(hin, row_ptr, csr, aggb);
        gemm_mfma<<<(NNODES + 127) / 128, 256, 0, stream>>>(aggb, hin, Wl, bb, batch, z, l, hout);
        hin = hout;
    }
    mlp1<<<NGRAPHS, 128, 0, stream>>>(z, gptr, Wl1, bl1, z2);
    mlp2<<<NGRAPHS, 128, 0, stream>>>(z2, Wl2, bl2, out);
}